// Round 1
// baseline (1196.819 us; speedup 1.0000x reference)
//
#include <hip/hip_runtime.h>
#include <hip/hip_bf16.h>

#define N_TOK 4096
#define DIM   1024
#define NEXP  8
#define FDIM  4096

#define BM 128
#define BN 128
#define BK 32
#define LDSP 40   // padded LDS row length (bf16 elems): 80B rows -> conflict-free b128 frag reads

typedef __attribute__((ext_vector_type(8))) short bf16x8;
typedef __attribute__((ext_vector_type(4))) float f32x4;

__device__ __forceinline__ unsigned short f2bf(float f) {
    unsigned u = __builtin_bit_cast(unsigned, f);
    u = (u + 0x7fffu + ((u >> 16) & 1u)) >> 16;
    return (unsigned short)u;
}

// ---------------- router: 1 wave per token ----------------
__global__ void router_kernel(const float* __restrict__ x, const float* __restrict__ Wr,
                              int* __restrict__ tk_idx, float* __restrict__ tk_w,
                              int* __restrict__ counts) {
    int n = blockIdx.x;
    int l = threadIdx.x;  // 0..63
    float acc[8];
#pragma unroll
    for (int e = 0; e < 8; e++) acc[e] = 0.f;
    const float* xr = x + (size_t)n * DIM;
#pragma unroll 4
    for (int i = 0; i < 16; i++) {
        int d = i * 64 + l;
        float xv = xr[d];
        const float4* wr = (const float4*)(Wr + (size_t)d * 8);
        float4 w0 = wr[0], w1 = wr[1];
        acc[0] += xv * w0.x; acc[1] += xv * w0.y; acc[2] += xv * w0.z; acc[3] += xv * w0.w;
        acc[4] += xv * w1.x; acc[5] += xv * w1.y; acc[6] += xv * w1.z; acc[7] += xv * w1.w;
    }
#pragma unroll
    for (int off = 32; off >= 1; off >>= 1)
#pragma unroll
        for (int e = 0; e < 8; e++) acc[e] += __shfl_xor(acc[e], off);
    if (l == 0) {
        float mx = acc[0];
#pragma unroll
        for (int e = 1; e < 8; e++) mx = fmaxf(mx, acc[e]);
        float p[8], s = 0.f;
#pragma unroll
        for (int e = 0; e < 8; e++) { p[e] = expf(acc[e] - mx); s += p[e]; }
#pragma unroll
        for (int e = 0; e < 8; e++) p[e] /= s;
        int i0 = 0;
#pragma unroll
        for (int e = 1; e < 8; e++) if (p[e] > p[i0]) i0 = e;
        int i1 = (i0 == 0) ? 1 : 0;
#pragma unroll
        for (int e = 0; e < 8; e++) if (e != i0 && p[e] > p[i1]) i1 = e;
        float w0 = p[i0], w1 = p[i1], s2 = w0 + w1;
        w0 /= s2; w1 /= s2;
        tk_idx[2 * n] = i0; tk_idx[2 * n + 1] = i1;
        tk_w[2 * n] = w0;   tk_w[2 * n + 1] = w1;
        atomicAdd(&counts[i0], 1);
        atomicAdd(&counts[i1], 1);
    }
}

__global__ void scan_kernel(const int* __restrict__ counts, int* __restrict__ offs,
                            int* __restrict__ cursor) {
    if (threadIdx.x == 0 && blockIdx.x == 0) {
        int a = 0;
        for (int e = 0; e < NEXP; e++) { offs[e] = a; cursor[e] = a; a += counts[e]; }
        offs[NEXP] = a;
    }
}

__global__ void fill_kernel(const int* __restrict__ tk_idx, int* __restrict__ cursor,
                            int* __restrict__ perm) {
    int n = blockIdx.x * blockDim.x + threadIdx.x;
    if (n >= N_TOK) return;
    int i0 = tk_idx[2 * n], i1 = tk_idx[2 * n + 1];
    int p0 = atomicAdd(&cursor[i0], 1);
    perm[p0] = 2 * n;
    int p1 = atomicAdd(&cursor[i1], 1);
    perm[p1] = 2 * n + 1;
}

// gather x rows (fp32) -> xb (bf16), permuted row space; 2 rows per block
__global__ void gather_kernel(const float* __restrict__ x, const int* __restrict__ perm,
                              unsigned short* __restrict__ xb) {
    int p = blockIdx.x * 2 + (threadIdx.x >> 7);
    int c = (threadIdx.x & 127) * 8;
    int tok = perm[p] >> 1;
    const float4* src = (const float4*)(x + (size_t)tok * DIM + c);
    float4 a = src[0], b = src[1];
    unsigned short o[8] = {f2bf(a.x), f2bf(a.y), f2bf(a.z), f2bf(a.w),
                           f2bf(b.x), f2bf(b.y), f2bf(b.z), f2bf(b.w)};
    *(int4*)(xb + (size_t)p * DIM + c) = *(const int4*)o;
}

// transpose + fp32->bf16: in [E][R][C] -> out [E][C][R]
__global__ void transpose_conv_kernel(const float* __restrict__ in, unsigned short* __restrict__ out,
                                      int R, int C) {
    __shared__ float tile[32][33];
    int e = blockIdx.z;
    const float* ip = in + (size_t)e * R * C;
    unsigned short* op = out + (size_t)e * R * C;
    int c0 = blockIdx.x * 32, r0 = blockIdx.y * 32;
    int tx = threadIdx.x, ty = threadIdx.y;
#pragma unroll
    for (int j = 0; j < 4; j++)
        tile[ty + j * 8][tx] = ip[(size_t)(r0 + ty + j * 8) * C + c0 + tx];
    __syncthreads();
#pragma unroll
    for (int j = 0; j < 4; j++)
        op[(size_t)(c0 + ty + j * 8) * R + r0 + tx] = f2bf(tile[tx][ty + j * 8]);
}

// ---------------- GEMM1: h = gelu(xb @ W1t^T), per expert ----------------
// A: xb rows [off,off+cnt) x K=1024 (bf16, row-major)
// B: w1t[e]: [4096][1024] (n-major, k-contiguous, bf16)
__global__ __launch_bounds__(256) void gemm1_kernel(
    const unsigned short* __restrict__ xb, const unsigned short* __restrict__ w1t,
    unsigned short* __restrict__ h, const int* __restrict__ counts, const int* __restrict__ offs) {
    const int K = DIM;
    int e = blockIdx.z;
    int cnt = counts[e];
    int rt = blockIdx.x;
    if (rt * BM >= cnt) return;
    int off = offs[e];
    int n0 = blockIdx.y * BN;
    const unsigned short* A = xb + (size_t)off * K;
    const unsigned short* B = w1t + (size_t)e * FDIM * DIM;

    __shared__ unsigned short As[BM * LDSP];
    __shared__ unsigned short Bs[BN * LDSP];

    int t = threadIdx.x;
    int lane = t & 63, wid = t >> 6;
    int wm = wid >> 1, wn = wid & 1;
    int arow_base = rt * BM;

    f32x4 acc[4][4];
#pragma unroll
    for (int i = 0; i < 4; i++)
#pragma unroll
        for (int j = 0; j < 4; j++) acc[i][j] = (f32x4){0.f, 0.f, 0.f, 0.f};

    int kl = (lane >> 4) * 8;
    int rl = lane & 15;

    for (int k0 = 0; k0 < K; k0 += BK) {
#pragma unroll
        for (int i = 0; i < 2; i++) {
            int id = t + i * 256;
            int row = id >> 2, c = (id & 3) * 8;
            int4 va = {0, 0, 0, 0};
            int gr = arow_base + row;
            if (gr < cnt) va = *(const int4*)(A + (size_t)gr * K + k0 + c);
            *(int4*)(As + row * LDSP + c) = va;
            int4 vb = *(const int4*)(B + (size_t)(n0 + row) * K + k0 + c);
            *(int4*)(Bs + row * LDSP + c) = vb;
        }
        __syncthreads();
        bf16x8 af[4], bfr[4];
#pragma unroll
        for (int mf = 0; mf < 4; mf++)
            af[mf] = *(const bf16x8*)(As + (wm * 64 + mf * 16 + rl) * LDSP + kl);
#pragma unroll
        for (int nf = 0; nf < 4; nf++)
            bfr[nf] = *(const bf16x8*)(Bs + (wn * 64 + nf * 16 + rl) * LDSP + kl);
#pragma unroll
        for (int mf = 0; mf < 4; mf++)
#pragma unroll
            for (int nf = 0; nf < 4; nf++)
                acc[mf][nf] = __builtin_amdgcn_mfma_f32_16x16x32_bf16(af[mf], bfr[nf], acc[mf][nf], 0, 0, 0);
        __syncthreads();
    }
    // epilogue: exact GELU, store bf16
    int rq = lane >> 4;
#pragma unroll
    for (int mf = 0; mf < 4; mf++) {
#pragma unroll
        for (int r = 0; r < 4; r++) {
            int row_local = wm * 64 + mf * 16 + rq * 4 + r;
            int grow = arow_base + row_local;
            if (grow < cnt) {
                unsigned short* hp = h + (size_t)(off + grow) * FDIM + n0 + wn * 64;
#pragma unroll
                for (int nf = 0; nf < 4; nf++) {
                    float v = acc[mf][nf][r];
                    float g = 0.5f * v * (1.0f + erff(v * 0.70710678118654752f));
                    hp[nf * 16 + rl] = f2bf(g);
                }
            }
        }
    }
}

// ---------------- GEMM2: y = h @ W2t^T, scatter-add weighted into out ----------------
__global__ __launch_bounds__(256) void gemm2_kernel(
    const unsigned short* __restrict__ h, const unsigned short* __restrict__ w2t,
    float* __restrict__ out, const int* __restrict__ counts, const int* __restrict__ offs,
    const int* __restrict__ perm, const float* __restrict__ tk_w) {
    const int K = FDIM;
    int e = blockIdx.z;
    int cnt = counts[e];
    int rt = blockIdx.x;
    if (rt * BM >= cnt) return;
    int off = offs[e];
    int n0 = blockIdx.y * BN;
    const unsigned short* A = h + (size_t)off * K;
    const unsigned short* B = w2t + (size_t)e * DIM * FDIM;

    __shared__ unsigned short As[BM * LDSP];
    __shared__ unsigned short Bs[BN * LDSP];

    int t = threadIdx.x;
    int lane = t & 63, wid = t >> 6;
    int wm = wid >> 1, wn = wid & 1;
    int arow_base = rt * BM;

    f32x4 acc[4][4];
#pragma unroll
    for (int i = 0; i < 4; i++)
#pragma unroll
        for (int j = 0; j < 4; j++) acc[i][j] = (f32x4){0.f, 0.f, 0.f, 0.f};

    int kl = (lane >> 4) * 8;
    int rl = lane & 15;

    for (int k0 = 0; k0 < K; k0 += BK) {
#pragma unroll
        for (int i = 0; i < 2; i++) {
            int id = t + i * 256;
            int row = id >> 2, c = (id & 3) * 8;
            int4 va = {0, 0, 0, 0};
            int gr = arow_base + row;
            if (gr < cnt) va = *(const int4*)(A + (size_t)gr * K + k0 + c);
            *(int4*)(As + row * LDSP + c) = va;
            int4 vb = *(const int4*)(B + (size_t)(n0 + row) * K + k0 + c);
            *(int4*)(Bs + row * LDSP + c) = vb;
        }
        __syncthreads();
        bf16x8 af[4], bfr[4];
#pragma unroll
        for (int mf = 0; mf < 4; mf++)
            af[mf] = *(const bf16x8*)(As + (wm * 64 + mf * 16 + rl) * LDSP + kl);
#pragma unroll
        for (int nf = 0; nf < 4; nf++)
            bfr[nf] = *(const bf16x8*)(Bs + (wn * 64 + nf * 16 + rl) * LDSP + kl);
#pragma unroll
        for (int mf = 0; mf < 4; mf++)
#pragma unroll
            for (int nf = 0; nf < 4; nf++)
                acc[mf][nf] = __builtin_amdgcn_mfma_f32_16x16x32_bf16(af[mf], bfr[nf], acc[mf][nf], 0, 0, 0);
        __syncthreads();
    }
    // epilogue: weighted scatter-add into out
    int rq = lane >> 4;
#pragma unroll
    for (int mf = 0; mf < 4; mf++) {
#pragma unroll
        for (int r = 0; r < 4; r++) {
            int row_local = wm * 64 + mf * 16 + rq * 4 + r;
            int grow = arow_base + row_local;
            if (grow < cnt) {
                int pv = perm[off + grow];
                float wgt = tk_w[pv];
                float* op = out + (size_t)(pv >> 1) * DIM + n0 + wn * 64;
#pragma unroll
                for (int nf = 0; nf < 4; nf++)
                    atomicAdd(&op[nf * 16 + rl], wgt * acc[mf][nf][r]);
            }
        }
    }
}

extern "C" void kernel_launch(void* const* d_in, const int* in_sizes, int n_in,
                              void* d_out, int out_size, void* d_ws, size_t ws_size,
                              hipStream_t stream) {
    const float* x  = (const float*)d_in[0];
    const float* Wr = (const float*)d_in[1];
    const float* W1 = (const float*)d_in[2];
    const float* W2 = (const float*)d_in[3];
    float* out = (float*)d_out;

    char* w = (char*)d_ws;
    int*   counts = (int*)(w + 0);
    int*   offs   = (int*)(w + 64);
    int*   cursor = (int*)(w + 128);
    int*   tk_idx = (int*)(w + 256);
    float* tk_w   = (float*)(w + 256 + 32768);
    int*   perm   = (int*)(w + 256 + 65536);
    size_t base = (size_t)1 << 20;
    unsigned short* xb   = (unsigned short*)(w + base);                          // 16 MB
    unsigned short* hbuf = (unsigned short*)(w + base + ((size_t)16 << 20));     // 64 MB
    unsigned short* w1t  = (unsigned short*)(w + base + ((size_t)80 << 20));     // 64 MB
    unsigned short* w2t  = (unsigned short*)(w + base + ((size_t)144 << 20));    // 64 MB

    hipMemsetAsync(d_out, 0, (size_t)out_size * sizeof(float), stream);
    hipMemsetAsync(w, 0, 256, stream);

    router_kernel<<<N_TOK, 64, 0, stream>>>(x, Wr, tk_idx, tk_w, counts);
    scan_kernel<<<1, 64, 0, stream>>>(counts, offs, cursor);
    fill_kernel<<<N_TOK / 256, 256, 0, stream>>>(tk_idx, cursor, perm);
    gather_kernel<<<N_TOK, 256, 0, stream>>>(x, perm, xb);  // 2N rows / 2 per block

    // W1 [E][1024][4096] -> w1t [E][4096][1024]
    transpose_conv_kernel<<<dim3(FDIM / 32, DIM / 32, NEXP), dim3(32, 8), 0, stream>>>(W1, w1t, DIM, FDIM);
    // W2 [E][4096][1024] -> w2t [E][1024][4096]
    transpose_conv_kernel<<<dim3(DIM / 32, FDIM / 32, NEXP), dim3(32, 8), 0, stream>>>(W2, w2t, FDIM, DIM);

    gemm1_kernel<<<dim3(N_TOK / BM, FDIM / BN, NEXP), 256, 0, stream>>>(xb, w1t, hbuf, counts, offs);
    gemm2_kernel<<<dim3(N_TOK / BM, DIM / BN, NEXP), 256, 0, stream>>>(hbuf, w2t, out, counts, offs, perm, tk_w);
}

// Round 2
// 953.816 us; speedup vs baseline: 1.2548x; 1.2548x over previous
//
#include <hip/hip_runtime.h>
#include <hip/hip_bf16.h>

#define N_TOK 4096
#define DIM   1024
#define NEXP  8
#define FDIM  4096

#define BM 128
#define BN 128
#define BK 32

typedef __attribute__((ext_vector_type(8))) short bf16x8;
typedef __attribute__((ext_vector_type(4))) float f32x4;

__device__ __forceinline__ unsigned short f2bf(float f) {
    unsigned u = __builtin_bit_cast(unsigned, f);
    u = (u + 0x7fffu + ((u >> 16) & 1u)) >> 16;
    return (unsigned short)u;
}

// async global->LDS, 16B per lane. LDS dest is wave-uniform base + lane*16.
__device__ __forceinline__ void gld16(const unsigned short* g, unsigned short* l) {
    __builtin_amdgcn_global_load_lds(
        (const __attribute__((address_space(1))) unsigned int*)g,
        (__attribute__((address_space(3))) unsigned int*)l, 16, 0, 0);
}

// ---------------- router: 1 wave per token ----------------
__global__ void router_kernel(const float* __restrict__ x, const float* __restrict__ Wr,
                              int* __restrict__ tk_idx, float* __restrict__ tk_w,
                              int* __restrict__ counts) {
    int n = blockIdx.x;
    int l = threadIdx.x;  // 0..63
    float acc[8];
#pragma unroll
    for (int e = 0; e < 8; e++) acc[e] = 0.f;
    const float* xr = x + (size_t)n * DIM;
#pragma unroll 4
    for (int i = 0; i < 16; i++) {
        int d = i * 64 + l;
        float xv = xr[d];
        const float4* wr = (const float4*)(Wr + (size_t)d * 8);
        float4 w0 = wr[0], w1 = wr[1];
        acc[0] += xv * w0.x; acc[1] += xv * w0.y; acc[2] += xv * w0.z; acc[3] += xv * w0.w;
        acc[4] += xv * w1.x; acc[5] += xv * w1.y; acc[6] += xv * w1.z; acc[7] += xv * w1.w;
    }
#pragma unroll
    for (int off = 32; off >= 1; off >>= 1)
#pragma unroll
        for (int e = 0; e < 8; e++) acc[e] += __shfl_xor(acc[e], off);
    if (l == 0) {
        float mx = acc[0];
#pragma unroll
        for (int e = 1; e < 8; e++) mx = fmaxf(mx, acc[e]);
        float p[8], s = 0.f;
#pragma unroll
        for (int e = 0; e < 8; e++) { p[e] = expf(acc[e] - mx); s += p[e]; }
#pragma unroll
        for (int e = 0; e < 8; e++) p[e] /= s;
        int i0 = 0;
#pragma unroll
        for (int e = 1; e < 8; e++) if (p[e] > p[i0]) i0 = e;
        int i1 = (i0 == 0) ? 1 : 0;
#pragma unroll
        for (int e = 0; e < 8; e++) if (e != i0 && p[e] > p[i1]) i1 = e;
        float w0 = p[i0], w1 = p[i1], s2 = w0 + w1;
        w0 /= s2; w1 /= s2;
        tk_idx[2 * n] = i0; tk_idx[2 * n + 1] = i1;
        tk_w[2 * n] = w0;   tk_w[2 * n + 1] = w1;
        atomicAdd(&counts[i0], 1);
        atomicAdd(&counts[i1], 1);
    }
}

__global__ void scan_kernel(const int* __restrict__ counts, int* __restrict__ offs,
                            int* __restrict__ cursor) {
    if (threadIdx.x == 0 && blockIdx.x == 0) {
        int a = 0;
        for (int e = 0; e < NEXP; e++) { offs[e] = a; cursor[e] = a; a += counts[e]; }
        offs[NEXP] = a;
    }
}

__global__ void fill_kernel(const int* __restrict__ tk_idx, int* __restrict__ cursor,
                            int* __restrict__ perm) {
    int n = blockIdx.x * blockDim.x + threadIdx.x;
    if (n >= N_TOK) return;
    int i0 = tk_idx[2 * n], i1 = tk_idx[2 * n + 1];
    int p0 = atomicAdd(&cursor[i0], 1);
    perm[p0] = 2 * n;
    int p1 = atomicAdd(&cursor[i1], 1);
    perm[p1] = 2 * n + 1;
}

// gather x rows (fp32) -> xb (bf16), permuted row space; 2 rows per block
__global__ void gather_kernel(const float* __restrict__ x, const int* __restrict__ perm,
                              unsigned short* __restrict__ xb) {
    int p = blockIdx.x * 2 + (threadIdx.x >> 7);
    int c = (threadIdx.x & 127) * 8;
    int tok = perm[p] >> 1;
    const float4* src = (const float4*)(x + (size_t)tok * DIM + c);
    float4 a = src[0], b = src[1];
    unsigned short o[8] = {f2bf(a.x), f2bf(a.y), f2bf(a.z), f2bf(a.w),
                           f2bf(b.x), f2bf(b.y), f2bf(b.z), f2bf(b.w)};
    *(int4*)(xb + (size_t)p * DIM + c) = *(const int4*)o;
}

// transpose + fp32->bf16: in [E][R][C] -> out [E][C][R]
__global__ void transpose_conv_kernel(const float* __restrict__ in, unsigned short* __restrict__ out,
                                      int R, int C) {
    __shared__ float tile[32][33];
    int e = blockIdx.z;
    const float* ip = in + (size_t)e * R * C;
    unsigned short* op = out + (size_t)e * R * C;
    int c0 = blockIdx.x * 32, r0 = blockIdx.y * 32;
    int tx = threadIdx.x, ty = threadIdx.y;
#pragma unroll
    for (int j = 0; j < 4; j++)
        tile[ty + j * 8][tx] = ip[(size_t)(r0 + ty + j * 8) * C + c0 + tx];
    __syncthreads();
#pragma unroll
    for (int j = 0; j < 4; j++)
        op[(size_t)(c0 + ty + j * 8) * R + r0 + tx] = f2bf(tile[tx][ty + j * 8]);
}

// ---------------- GEMM core (m97 structure): linear LDS + global_load_lds(16B) ----------------
// A: rows [off,off+cnt) x K (bf16 row-major, k-contiguous), rows >= cnt clamped (discarded later)
// B: [n][K] (bf16 row-major, k-contiguous)

// GEMM1: h = gelu(xb @ w1t^T)  (K = 1024, N = 4096)
__global__ __launch_bounds__(256) void gemm1_kernel(
    const unsigned short* __restrict__ xb, const unsigned short* __restrict__ w1t,
    unsigned short* __restrict__ h, const int* __restrict__ counts, const int* __restrict__ offs) {
    const int K = DIM;
    int e = blockIdx.z;
    int cnt = counts[e];
    int rt = blockIdx.x;
    if (rt * BM >= cnt) return;
    int off = offs[e];
    int n0 = blockIdx.y * BN;
    const unsigned short* A = xb + (size_t)off * K;
    const unsigned short* B = w1t + (size_t)e * FDIM * DIM;

    __shared__ unsigned short As[BM * BK];
    __shared__ unsigned short Bs[BN * BK];

    int t = threadIdx.x;
    int lane = t & 63, wid = t >> 6;
    int wm = wid >> 1, wn = wid & 1;
    int arow_base = rt * BM;

    // staging: per wave, 2 A-loads + 2 B-loads of 1KB (16 rows) each
    int lrow = lane >> 2;          // 0..15
    int lcol = (lane & 3) * 8;     // element col within 32-wide K-slab
    int ra0 = min(arow_base + wid * 32 + lrow, cnt - 1);
    int ra1 = min(arow_base + wid * 32 + 16 + lrow, cnt - 1);
    const unsigned short* pA0 = A + (size_t)ra0 * K + lcol;
    const unsigned short* pA1 = A + (size_t)ra1 * K + lcol;
    const unsigned short* pB0 = B + (size_t)(n0 + wid * 32 + lrow) * K + lcol;
    const unsigned short* pB1 = pB0 + (size_t)16 * K;
    unsigned short* lA0 = As + (wid * 32) * BK;
    unsigned short* lA1 = As + (wid * 32 + 16) * BK;
    unsigned short* lB0 = Bs + (wid * 32) * BK;
    unsigned short* lB1 = Bs + (wid * 32 + 16) * BK;

    f32x4 acc[4][4];
#pragma unroll
    for (int i = 0; i < 4; i++)
#pragma unroll
        for (int j = 0; j < 4; j++) acc[i][j] = (f32x4){0.f, 0.f, 0.f, 0.f};

    int kl = (lane >> 4) * 8;
    int rl = lane & 15;

    for (int k0 = 0; k0 < K; k0 += BK) {
        gld16(pA0, lA0); gld16(pA1, lA1);
        gld16(pB0, lB0); gld16(pB1, lB1);
        pA0 += BK; pA1 += BK; pB0 += BK; pB1 += BK;
        __syncthreads();   // drains vmcnt -> staged data visible
        bf16x8 af[4], bfr[4];
#pragma unroll
        for (int mf = 0; mf < 4; mf++)
            af[mf] = *(const bf16x8*)(As + (wm * 64 + mf * 16 + rl) * BK + kl);
#pragma unroll
        for (int nf = 0; nf < 4; nf++)
            bfr[nf] = *(const bf16x8*)(Bs + (wn * 64 + nf * 16 + rl) * BK + kl);
#pragma unroll
        for (int mf = 0; mf < 4; mf++)
#pragma unroll
            for (int nf = 0; nf < 4; nf++)
                acc[mf][nf] = __builtin_amdgcn_mfma_f32_16x16x32_bf16(af[mf], bfr[nf], acc[mf][nf], 0, 0, 0);
        __syncthreads();   // all reads done before next iteration overwrites LDS
    }
    // epilogue: exact GELU, store bf16
    int rq = lane >> 4;
#pragma unroll
    for (int mf = 0; mf < 4; mf++) {
#pragma unroll
        for (int r = 0; r < 4; r++) {
            int row_local = wm * 64 + mf * 16 + rq * 4 + r;
            int grow = arow_base + row_local;
            if (grow < cnt) {
                unsigned short* hp = h + (size_t)(off + grow) * FDIM + n0 + wn * 64;
#pragma unroll
                for (int nf = 0; nf < 4; nf++) {
                    float v = acc[mf][nf][r];
                    float g = 0.5f * v * (1.0f + erff(v * 0.70710678118654752f));
                    hp[nf * 16 + rl] = f2bf(g);
                }
            }
        }
    }
}

// GEMM2: y = h @ w2t^T, weighted scatter-add into out  (K = 4096, N = 1024)
__global__ __launch_bounds__(256) void gemm2_kernel(
    const unsigned short* __restrict__ h, const unsigned short* __restrict__ w2t,
    float* __restrict__ out, const int* __restrict__ counts, const int* __restrict__ offs,
    const int* __restrict__ perm, const float* __restrict__ tk_w) {
    const int K = FDIM;
    int e = blockIdx.z;
    int cnt = counts[e];
    int rt = blockIdx.x;
    if (rt * BM >= cnt) return;
    int off = offs[e];
    int n0 = blockIdx.y * BN;
    const unsigned short* A = h + (size_t)off * K;
    const unsigned short* B = w2t + (size_t)e * DIM * FDIM;

    __shared__ unsigned short As[BM * BK];
    __shared__ unsigned short Bs[BN * BK];

    int t = threadIdx.x;
    int lane = t & 63, wid = t >> 6;
    int wm = wid >> 1, wn = wid & 1;
    int arow_base = rt * BM;

    int lrow = lane >> 2;
    int lcol = (lane & 3) * 8;
    int ra0 = min(arow_base + wid * 32 + lrow, cnt - 1);
    int ra1 = min(arow_base + wid * 32 + 16 + lrow, cnt - 1);
    const unsigned short* pA0 = A + (size_t)ra0 * K + lcol;
    const unsigned short* pA1 = A + (size_t)ra1 * K + lcol;
    const unsigned short* pB0 = B + (size_t)(n0 + wid * 32 + lrow) * K + lcol;
    const unsigned short* pB1 = pB0 + (size_t)16 * K;
    unsigned short* lA0 = As + (wid * 32) * BK;
    unsigned short* lA1 = As + (wid * 32 + 16) * BK;
    unsigned short* lB0 = Bs + (wid * 32) * BK;
    unsigned short* lB1 = Bs + (wid * 32 + 16) * BK;

    f32x4 acc[4][4];
#pragma unroll
    for (int i = 0; i < 4; i++)
#pragma unroll
        for (int j = 0; j < 4; j++) acc[i][j] = (f32x4){0.f, 0.f, 0.f, 0.f};

    int kl = (lane >> 4) * 8;
    int rl = lane & 15;

    for (int k0 = 0; k0 < K; k0 += BK) {
        gld16(pA0, lA0); gld16(pA1, lA1);
        gld16(pB0, lB0); gld16(pB1, lB1);
        pA0 += BK; pA1 += BK; pB0 += BK; pB1 += BK;
        __syncthreads();
        bf16x8 af[4], bfr[4];
#pragma unroll
        for (int mf = 0; mf < 4; mf++)
            af[mf] = *(const bf16x8*)(As + (wm * 64 + mf * 16 + rl) * BK + kl);
#pragma unroll
        for (int nf = 0; nf < 4; nf++)
            bfr[nf] = *(const bf16x8*)(Bs + (wn * 64 + nf * 16 + rl) * BK + kl);
#pragma unroll
        for (int mf = 0; mf < 4; mf++)
#pragma unroll
            for (int nf = 0; nf < 4; nf++)
                acc[mf][nf] = __builtin_amdgcn_mfma_f32_16x16x32_bf16(af[mf], bfr[nf], acc[mf][nf], 0, 0, 0);
        __syncthreads();
    }
    // epilogue: weighted scatter-add into out
    int rq = lane >> 4;
#pragma unroll
    for (int mf = 0; mf < 4; mf++) {
#pragma unroll
        for (int r = 0; r < 4; r++) {
            int row_local = wm * 64 + mf * 16 + rq * 4 + r;
            int grow = arow_base + row_local;
            if (grow < cnt) {
                int pv = perm[off + grow];
                float wgt = tk_w[pv];
                float* op = out + (size_t)(pv >> 1) * DIM + n0 + wn * 64;
#pragma unroll
                for (int nf = 0; nf < 4; nf++)
                    atomicAdd(&op[nf * 16 + rl], wgt * acc[mf][nf][r]);
            }
        }
    }
}

extern "C" void kernel_launch(void* const* d_in, const int* in_sizes, int n_in,
                              void* d_out, int out_size, void* d_ws, size_t ws_size,
                              hipStream_t stream) {
    const float* x  = (const float*)d_in[0];
    const float* Wr = (const float*)d_in[1];
    const float* W1 = (const float*)d_in[2];
    const float* W2 = (const float*)d_in[3];
    float* out = (float*)d_out;

    char* w = (char*)d_ws;
    int*   counts = (int*)(w + 0);
    int*   offs   = (int*)(w + 64);
    int*   cursor = (int*)(w + 128);
    int*   tk_idx = (int*)(w + 256);
    float* tk_w   = (float*)(w + 256 + 32768);
    int*   perm   = (int*)(w + 256 + 65536);
    size_t base = (size_t)1 << 20;
    unsigned short* xb   = (unsigned short*)(w + base);                          // 16 MB
    unsigned short* hbuf = (unsigned short*)(w + base + ((size_t)16 << 20));     // 64 MB
    unsigned short* w1t  = (unsigned short*)(w + base + ((size_t)80 << 20));     // 64 MB
    unsigned short* w2t  = (unsigned short*)(w + base + ((size_t)144 << 20));    // 64 MB

    hipMemsetAsync(d_out, 0, (size_t)out_size * sizeof(float), stream);
    hipMemsetAsync(w, 0, 256, stream);

    router_kernel<<<N_TOK, 64, 0, stream>>>(x, Wr, tk_idx, tk_w, counts);
    scan_kernel<<<1, 64, 0, stream>>>(counts, offs, cursor);
    fill_kernel<<<N_TOK / 256, 256, 0, stream>>>(tk_idx, cursor, perm);
    gather_kernel<<<N_TOK, 256, 0, stream>>>(x, perm, xb);

    // W1 [E][1024][4096] -> w1t [E][4096][1024]
    transpose_conv_kernel<<<dim3(FDIM / 32, DIM / 32, NEXP), dim3(32, 8), 0, stream>>>(W1, w1t, DIM, FDIM);
    // W2 [E][4096][1024] -> w2t [E][1024][4096]
    transpose_conv_kernel<<<dim3(DIM / 32, FDIM / 32, NEXP), dim3(32, 8), 0, stream>>>(W2, w2t, FDIM, DIM);

    gemm1_kernel<<<dim3(N_TOK / BM, FDIM / BN, NEXP), 256, 0, stream>>>(xb, w1t, hbuf, counts, offs);
    gemm2_kernel<<<dim3(N_TOK / BM, DIM / BN, NEXP), 256, 0, stream>>>(hbuf, w2t, out, counts, offs, perm, tk_w);
}

// Round 3
// 552.601 us; speedup vs baseline: 2.1658x; 1.7260x over previous
//
#include <hip/hip_runtime.h>
#include <hip/hip_bf16.h>

#define N_TOK 4096
#define DIM   1024
#define NEXP  8
#define FDIM  4096

#define BM 128
#define BN 128
#define BK 32
#define BMBK (BM * BK)

typedef __attribute__((ext_vector_type(8))) short bf16x8;
typedef __attribute__((ext_vector_type(4))) float f32x4;

__device__ __forceinline__ unsigned short f2bf(float f) {
    unsigned u = __builtin_bit_cast(unsigned, f);
    u = (u + 0x7fffu + ((u >> 16) & 1u)) >> 16;
    return (unsigned short)u;
}

// async global->LDS, 16B per lane. LDS dest is wave-uniform base + lane*16.
__device__ __forceinline__ void gld16(const unsigned short* g, unsigned short* l) {
    __builtin_amdgcn_global_load_lds(
        (const __attribute__((address_space(1))) unsigned int*)g,
        (__attribute__((address_space(3))) unsigned int*)l, 16, 0, 0);
}

// ---------------- router: 1 wave per token ----------------
__global__ void router_kernel(const float* __restrict__ x, const float* __restrict__ Wr,
                              int* __restrict__ tk_idx, float* __restrict__ tk_w,
                              int* __restrict__ counts) {
    int n = blockIdx.x;
    int l = threadIdx.x;  // 0..63
    float acc[8];
#pragma unroll
    for (int e = 0; e < 8; e++) acc[e] = 0.f;
    const float* xr = x + (size_t)n * DIM;
#pragma unroll 4
    for (int i = 0; i < 16; i++) {
        int d = i * 64 + l;
        float xv = xr[d];
        const float4* wr = (const float4*)(Wr + (size_t)d * 8);
        float4 w0 = wr[0], w1 = wr[1];
        acc[0] += xv * w0.x; acc[1] += xv * w0.y; acc[2] += xv * w0.z; acc[3] += xv * w0.w;
        acc[4] += xv * w1.x; acc[5] += xv * w1.y; acc[6] += xv * w1.z; acc[7] += xv * w1.w;
    }
#pragma unroll
    for (int off = 32; off >= 1; off >>= 1)
#pragma unroll
        for (int e = 0; e < 8; e++) acc[e] += __shfl_xor(acc[e], off);
    if (l == 0) {
        float mx = acc[0];
#pragma unroll
        for (int e = 1; e < 8; e++) mx = fmaxf(mx, acc[e]);
        float p[8], s = 0.f;
#pragma unroll
        for (int e = 0; e < 8; e++) { p[e] = expf(acc[e] - mx); s += p[e]; }
#pragma unroll
        for (int e = 0; e < 8; e++) p[e] /= s;
        int i0 = 0;
#pragma unroll
        for (int e = 1; e < 8; e++) if (p[e] > p[i0]) i0 = e;
        int i1 = (i0 == 0) ? 1 : 0;
#pragma unroll
        for (int e = 0; e < 8; e++) if (e != i0 && p[e] > p[i1]) i1 = e;
        float w0 = p[i0], w1 = p[i1], s2 = w0 + w1;
        w0 /= s2; w1 /= s2;
        tk_idx[2 * n] = i0; tk_idx[2 * n + 1] = i1;
        tk_w[2 * n] = w0;   tk_w[2 * n + 1] = w1;
        atomicAdd(&counts[i0], 1);
        atomicAdd(&counts[i1], 1);
    }
}

__global__ void scan_kernel(const int* __restrict__ counts, int* __restrict__ offs,
                            int* __restrict__ cursor) {
    if (threadIdx.x == 0 && blockIdx.x == 0) {
        int a = 0;
        for (int e = 0; e < NEXP; e++) { offs[e] = a; cursor[e] = a; a += counts[e]; }
        offs[NEXP] = a;
    }
}

__global__ void fill_kernel(const int* __restrict__ tk_idx, int* __restrict__ cursor,
                            int* __restrict__ perm) {
    int n = blockIdx.x * blockDim.x + threadIdx.x;
    if (n >= N_TOK) return;
    int i0 = tk_idx[2 * n], i1 = tk_idx[2 * n + 1];
    int p0 = atomicAdd(&cursor[i0], 1);
    perm[p0] = 2 * n;
    int p1 = atomicAdd(&cursor[i1], 1);
    perm[p1] = 2 * n + 1;
}

// gather x rows (fp32) -> xb (bf16), permuted row space; 2 rows per block
__global__ void gather_kernel(const float* __restrict__ x, const int* __restrict__ perm,
                              unsigned short* __restrict__ xb) {
    int p = blockIdx.x * 2 + (threadIdx.x >> 7);
    int c = (threadIdx.x & 127) * 8;
    int tok = perm[p] >> 1;
    const float4* src = (const float4*)(x + (size_t)tok * DIM + c);
    float4 a = src[0], b = src[1];
    unsigned short o[8] = {f2bf(a.x), f2bf(a.y), f2bf(a.z), f2bf(a.w),
                           f2bf(b.x), f2bf(b.y), f2bf(b.z), f2bf(b.w)};
    *(int4*)(xb + (size_t)p * DIM + c) = *(const int4*)o;
}

// transpose + fp32->bf16: in [E][R][C] -> out [E][C][R]
__global__ void transpose_conv_kernel(const float* __restrict__ in, unsigned short* __restrict__ out,
                                      int R, int C) {
    __shared__ float tile[32][33];
    int e = blockIdx.z;
    const float* ip = in + (size_t)e * R * C;
    unsigned short* op = out + (size_t)e * R * C;
    int c0 = blockIdx.x * 32, r0 = blockIdx.y * 32;
    int tx = threadIdx.x, ty = threadIdx.y;
#pragma unroll
    for (int j = 0; j < 4; j++)
        tile[ty + j * 8][tx] = ip[(size_t)(r0 + ty + j * 8) * C + c0 + tx];
    __syncthreads();
#pragma unroll
    for (int j = 0; j < 4; j++)
        op[(size_t)(c0 + ty + j * 8) * R + r0 + tx] = f2bf(tile[tx][ty + j * 8]);
}

// ---------------- GEMM core: 2-phase pipeline (prefetch dbuf) + XCD swizzle ----------------
// A: rows [off,off+cnt) x K (bf16 row-major, k-contiguous), rows >= cnt clamped
// B: [n][K] (bf16 row-major, k-contiguous)

// GEMM1: h = gelu(xb @ w1t^T)  (K = 1024, N = 4096); grid 1-D = 32*32*8
__global__ __launch_bounds__(256) void gemm1_kernel(
    const unsigned short* __restrict__ xb, const unsigned short* __restrict__ w1t,
    unsigned short* __restrict__ h, const int* __restrict__ counts, const int* __restrict__ offs) {
    const int K = DIM;
    const int NTX = N_TOK / BM;                 // 32
    const int NTY = FDIM / BN;                  // 32
    const int nwg = NTX * NTY * NEXP;           // 8192, %8==0
    // XCD chunked swizzle: consecutive logical tiles (same B-panel) stay on one XCD
    int L = blockIdx.x;
    int pos = (L & 7) * (nwg >> 3) + (L >> 3);
    int rt = pos % NTX;
    int tmp = pos / NTX;
    int n0 = (tmp % NTY) * BN;
    int e = tmp / NTY;

    int cnt = counts[e];
    if (rt * BM >= cnt) return;
    int off = offs[e];
    const unsigned short* A = xb + (size_t)off * K;
    const unsigned short* B = w1t + (size_t)e * FDIM * DIM;

    __shared__ unsigned short As[2 * BMBK];
    __shared__ unsigned short Bs[2 * BMBK];

    int t = threadIdx.x;
    int lane = t & 63, wid = t >> 6;
    int wm = wid >> 1, wn = wid & 1;
    int arow_base = rt * BM;

    int lrow = lane >> 2;          // 0..15
    int lcol = (lane & 3) * 8;     // elem col in 32-wide K-slab
    int ra0 = min(arow_base + wid * 32 + lrow, cnt - 1);
    int ra1 = min(arow_base + wid * 32 + 16 + lrow, cnt - 1);
    const unsigned short* pA0 = A + (size_t)ra0 * K + lcol;
    const unsigned short* pA1 = A + (size_t)ra1 * K + lcol;
    const unsigned short* pB0 = B + (size_t)(n0 + wid * 32 + lrow) * K + lcol;
    const unsigned short* pB1 = pB0 + (size_t)16 * K;
    int ldsA0 = (wid * 32) * BK, ldsA1 = (wid * 32 + 16) * BK;

    f32x4 acc[4][4];
#pragma unroll
    for (int i = 0; i < 4; i++)
#pragma unroll
        for (int j = 0; j < 4; j++) acc[i][j] = (f32x4){0.f, 0.f, 0.f, 0.f};

    int kl = (lane >> 4) * 8;
    int rl = lane & 15;

    auto stage = [&](int buf) {
        int bo = buf * BMBK;
        gld16(pA0, As + bo + ldsA0); gld16(pA1, As + bo + ldsA1);
        gld16(pB0, Bs + bo + ldsA0); gld16(pB1, Bs + bo + ldsA1);
        pA0 += BK; pA1 += BK; pB0 += BK; pB1 += BK;
    };
    auto compute = [&](int buf) {
        int bo = buf * BMBK;
        bf16x8 af[4], bfr[4];
#pragma unroll
        for (int mf = 0; mf < 4; mf++)
            af[mf] = *(const bf16x8*)(As + bo + (wm * 64 + mf * 16 + rl) * BK + kl);
#pragma unroll
        for (int nf = 0; nf < 4; nf++)
            bfr[nf] = *(const bf16x8*)(Bs + bo + (wn * 64 + nf * 16 + rl) * BK + kl);
#pragma unroll
        for (int mf = 0; mf < 4; mf++)
#pragma unroll
            for (int nf = 0; nf < 4; nf++)
                acc[mf][nf] = __builtin_amdgcn_mfma_f32_16x16x32_bf16(af[mf], bfr[nf], acc[mf][nf], 0, 0, 0);
    };

    const int NT = K / BK;
    stage(0);
    __syncthreads();
    int cur = 0;
    for (int it = 0; it < NT - 1; ++it) {
        stage(cur ^ 1);        // issue next tile's loads (latency hides under compute)
        compute(cur);
        __syncthreads();       // single full drain per K-step
        cur ^= 1;
    }
    compute(cur);

    // epilogue: exact GELU, store bf16
    int rq = lane >> 4;
#pragma unroll
    for (int mf = 0; mf < 4; mf++) {
#pragma unroll
        for (int r = 0; r < 4; r++) {
            int row_local = wm * 64 + mf * 16 + rq * 4 + r;
            int grow = arow_base + row_local;
            if (grow < cnt) {
                unsigned short* hp = h + (size_t)(off + grow) * FDIM + n0 + wn * 64;
#pragma unroll
                for (int nf = 0; nf < 4; nf++) {
                    float v = acc[mf][nf][r];
                    float g = 0.5f * v * (1.0f + erff(v * 0.70710678118654752f));
                    hp[nf * 16 + rl] = f2bf(g);
                }
            }
        }
    }
}

// GEMM2: y = h @ w2t^T, weighted scatter-add into out  (K = 4096, N = 1024); grid 1-D = 32*8*8
__global__ __launch_bounds__(256) void gemm2_kernel(
    const unsigned short* __restrict__ h, const unsigned short* __restrict__ w2t,
    float* __restrict__ out, const int* __restrict__ counts, const int* __restrict__ offs,
    const int* __restrict__ perm, const float* __restrict__ tk_w) {
    const int K = FDIM;
    const int NTX = N_TOK / BM;                 // 32
    const int NTY = DIM / BN;                   // 8
    const int nwg = NTX * NTY * NEXP;           // 2048, %8==0
    int L = blockIdx.x;
    int pos = (L & 7) * (nwg >> 3) + (L >> 3);
    int rt = pos % NTX;
    int tmp = pos / NTX;
    int n0 = (tmp % NTY) * BN;
    int e = tmp / NTY;

    int cnt = counts[e];
    if (rt * BM >= cnt) return;
    int off = offs[e];
    const unsigned short* A = h + (size_t)off * K;
    const unsigned short* B = w2t + (size_t)e * DIM * FDIM;

    __shared__ unsigned short As[2 * BMBK];
    __shared__ unsigned short Bs[2 * BMBK];

    int t = threadIdx.x;
    int lane = t & 63, wid = t >> 6;
    int wm = wid >> 1, wn = wid & 1;
    int arow_base = rt * BM;

    int lrow = lane >> 2;
    int lcol = (lane & 3) * 8;
    int ra0 = min(arow_base + wid * 32 + lrow, cnt - 1);
    int ra1 = min(arow_base + wid * 32 + 16 + lrow, cnt - 1);
    const unsigned short* pA0 = A + (size_t)ra0 * K + lcol;
    const unsigned short* pA1 = A + (size_t)ra1 * K + lcol;
    const unsigned short* pB0 = B + (size_t)(n0 + wid * 32 + lrow) * K + lcol;
    const unsigned short* pB1 = pB0 + (size_t)16 * K;
    int ldsA0 = (wid * 32) * BK, ldsA1 = (wid * 32 + 16) * BK;

    f32x4 acc[4][4];
#pragma unroll
    for (int i = 0; i < 4; i++)
#pragma unroll
        for (int j = 0; j < 4; j++) acc[i][j] = (f32x4){0.f, 0.f, 0.f, 0.f};

    int kl = (lane >> 4) * 8;
    int rl = lane & 15;

    auto stage = [&](int buf) {
        int bo = buf * BMBK;
        gld16(pA0, As + bo + ldsA0); gld16(pA1, As + bo + ldsA1);
        gld16(pB0, Bs + bo + ldsA0); gld16(pB1, Bs + bo + ldsA1);
        pA0 += BK; pA1 += BK; pB0 += BK; pB1 += BK;
    };
    auto compute = [&](int buf) {
        int bo = buf * BMBK;
        bf16x8 af[4], bfr[4];
#pragma unroll
        for (int mf = 0; mf < 4; mf++)
            af[mf] = *(const bf16x8*)(As + bo + (wm * 64 + mf * 16 + rl) * BK + kl);
#pragma unroll
        for (int nf = 0; nf < 4; nf++)
            bfr[nf] = *(const bf16x8*)(Bs + bo + (wn * 64 + nf * 16 + rl) * BK + kl);
#pragma unroll
        for (int mf = 0; mf < 4; mf++)
#pragma unroll
            for (int nf = 0; nf < 4; nf++)
                acc[mf][nf] = __builtin_amdgcn_mfma_f32_16x16x32_bf16(af[mf], bfr[nf], acc[mf][nf], 0, 0, 0);
    };

    const int NT = K / BK;
    stage(0);
    __syncthreads();
    int cur = 0;
    for (int it = 0; it < NT - 1; ++it) {
        stage(cur ^ 1);
        compute(cur);
        __syncthreads();
        cur ^= 1;
    }
    compute(cur);

    // epilogue: weighted scatter-add into out
    int rq = lane >> 4;
#pragma unroll
    for (int mf = 0; mf < 4; mf++) {
#pragma unroll
        for (int r = 0; r < 4; r++) {
            int row_local = wm * 64 + mf * 16 + rq * 4 + r;
            int grow = arow_base + row_local;
            if (grow < cnt) {
                int pv = perm[off + grow];
                float wgt = tk_w[pv];
                float* op = out + (size_t)(pv >> 1) * DIM + n0 + wn * 64;
#pragma unroll
                for (int nf = 0; nf < 4; nf++)
                    atomicAdd(&op[nf * 16 + rl], wgt * acc[mf][nf][r]);
            }
        }
    }
}

extern "C" void kernel_launch(void* const* d_in, const int* in_sizes, int n_in,
                              void* d_out, int out_size, void* d_ws, size_t ws_size,
                              hipStream_t stream) {
    const float* x  = (const float*)d_in[0];
    const float* Wr = (const float*)d_in[1];
    const float* W1 = (const float*)d_in[2];
    const float* W2 = (const float*)d_in[3];
    float* out = (float*)d_out;

    char* w = (char*)d_ws;
    int*   counts = (int*)(w + 0);
    int*   offs   = (int*)(w + 64);
    int*   cursor = (int*)(w + 128);
    int*   tk_idx = (int*)(w + 256);
    float* tk_w   = (float*)(w + 256 + 32768);
    int*   perm   = (int*)(w + 256 + 65536);
    size_t base = (size_t)1 << 20;
    unsigned short* xb   = (unsigned short*)(w + base);                          // 16 MB
    unsigned short* hbuf = (unsigned short*)(w + base + ((size_t)16 << 20));     // 64 MB
    unsigned short* w1t  = (unsigned short*)(w + base + ((size_t)80 << 20));     // 64 MB
    unsigned short* w2t  = (unsigned short*)(w + base + ((size_t)144 << 20));    // 64 MB

    hipMemsetAsync(d_out, 0, (size_t)out_size * sizeof(float), stream);
    hipMemsetAsync(w, 0, 256, stream);

    router_kernel<<<N_TOK, 64, 0, stream>>>(x, Wr, tk_idx, tk_w, counts);
    scan_kernel<<<1, 64, 0, stream>>>(counts, offs, cursor);
    fill_kernel<<<N_TOK / 256, 256, 0, stream>>>(tk_idx, cursor, perm);
    gather_kernel<<<N_TOK, 256, 0, stream>>>(x, perm, xb);

    // W1 [E][1024][4096] -> w1t [E][4096][1024]
    transpose_conv_kernel<<<dim3(FDIM / 32, DIM / 32, NEXP), dim3(32, 8), 0, stream>>>(W1, w1t, DIM, FDIM);
    // W2 [E][4096][1024] -> w2t [E][1024][4096]
    transpose_conv_kernel<<<dim3(DIM / 32, FDIM / 32, NEXP), dim3(32, 8), 0, stream>>>(W2, w2t, FDIM, DIM);

    gemm1_kernel<<<(N_TOK / BM) * (FDIM / BN) * NEXP, 256, 0, stream>>>(xb, w1t, hbuf, counts, offs);
    gemm2_kernel<<<(N_TOK / BM) * (DIM / BN) * NEXP, 256, 0, stream>>>(hbuf, w2t, out, counts, offs, perm, tk_w);
}